// Round 6
// baseline (399.513 us; speedup 1.0000x reference)
//
#include <hip/hip_runtime.h>

#define D 128

typedef __attribute__((ext_vector_type(8))) short bf16x8;
typedef __attribute__((ext_vector_type(4))) float f32x4;

__device__ __forceinline__ unsigned short f2b(float v) {
    unsigned u = __float_as_uint(v);
    unsigned r = u + 0x7fffu + ((u >> 16) & 1u);   // RNE, inputs never NaN
    return (unsigned short)(r >> 16);
}
__device__ __forceinline__ float b2f(unsigned short h) {
    return __uint_as_float(((unsigned)h) << 16);
}

// ---------------- graph preprocessing ----------------

__global__ void hist_kernel(const int* __restrict__ dst, int* __restrict__ cnt, int E) {
    int e = blockIdx.x * blockDim.x + threadIdx.x;
    if (e < E) atomicAdd(&cnt[dst[e]], 1);
}

// ---- 3-phase multi-block exclusive scan over cnt[N] ----

__global__ __launch_bounds__(256) void scan_phase1(const int* __restrict__ cnt,
                                                   int* __restrict__ bsum, int N) {
    int t = threadIdx.x;
    int base = blockIdx.x * 1024 + t * 4;
    int s = 0;
    if (base + 4 <= N) {
        int4 v = *(const int4*)(cnt + base);
        s = v.x + v.y + v.z + v.w;
    } else {
        for (int k = 0; k < 4; ++k)
            if (base + k < N) s += cnt[base + k];
    }
    for (int off = 32; off; off >>= 1) s += __shfl_down(s, off);
    __shared__ int ws[4];
    if ((t & 63) == 0) ws[t >> 6] = s;
    __syncthreads();
    if (t == 0) bsum[blockIdx.x] = ws[0] + ws[1] + ws[2] + ws[3];
}

__global__ __launch_bounds__(256) void scan_phase2(const int* __restrict__ bsum,
                                                   int* __restrict__ boff,
                                                   int* __restrict__ rs, int nb, int N) {
    __shared__ int sh[256];
    int t = threadIdx.x;
    int v = (t < nb) ? bsum[t] : 0;
    sh[t] = v;
    __syncthreads();
    for (int off = 1; off < 256; off <<= 1) {
        int o = (t >= off) ? sh[t - off] : 0;
        __syncthreads();
        sh[t] += o;
        __syncthreads();
    }
    if (t < nb) boff[t] = sh[t] - v;
    if (t == 255) rs[N] = sh[255];  // == E
}

__global__ __launch_bounds__(256) void scan_phase3(const int* __restrict__ cnt,
                                                   const int* __restrict__ boff,
                                                   int* __restrict__ rs, int* __restrict__ fp,
                                                   float* __restrict__ dinv, int N) {
    __shared__ int tsum[256];
    int t = threadIdx.x;
    int base = blockIdx.x * 1024 + t * 4;
    int v[4];
    int s = 0;
    if (base + 4 <= N) {
        int4 vv = *(const int4*)(cnt + base);
        v[0] = vv.x; v[1] = vv.y; v[2] = vv.z; v[3] = vv.w;
        s = v[0] + v[1] + v[2] + v[3];
    } else {
        for (int k = 0; k < 4; ++k) {
            v[k] = (base + k < N) ? cnt[base + k] : 0;
            s += v[k];
        }
    }
    tsum[t] = s;
    __syncthreads();
    for (int off = 1; off < 256; off <<= 1) {
        int o = (t >= off) ? tsum[t - off] : 0;
        __syncthreads();
        tsum[t] += o;
        __syncthreads();
    }
    int run = boff[blockIdx.x] + tsum[t] - s;
#pragma unroll
    for (int k = 0; k < 4; ++k) {
        int idx = base + k;
        if (idx < N) {
            rs[idx] = run;
            fp[idx] = run;
            dinv[idx] = rsqrtf((float)(v[k] + 1));  // +1 self-loop
            run += v[k];
        }
    }
}

// CSR fill with packed (src, dinv[src]) payload -> one 8B scatter per edge
__global__ void fill_kernel(const int* __restrict__ src, const int* __restrict__ dst,
                            const float* __restrict__ dinv,
                            int* __restrict__ fp, int2* __restrict__ colvw, int E) {
    int e = blockIdx.x * blockDim.x + threadIdx.x;
    if (e < E) {
        int s = src[e];
        int slot = atomicAdd(&fp[dst[e]], 1);
        int2 p;
        p.x = s;
        p.y = __float_as_int(dinv[s]);
        colvw[slot] = p;
    }
}

// three W[128,128] fp32 -> bf16-hi transposed [n][k], one launch
__global__ void wsplit3_kernel(const float* __restrict__ W1, const float* __restrict__ W2,
                               const float* __restrict__ Wq,
                               unsigned short* __restrict__ o1, unsigned short* __restrict__ o2,
                               unsigned short* __restrict__ oq) {
    int t = blockIdx.x * blockDim.x + threadIdx.x;  // 3 * 16384
    int which = t >> 14;
    int r = t & 16383;
    int n = r >> 7, k = r & 127;
    const float* W = (which == 0) ? W1 : (which == 1) ? W2 : Wq;
    unsigned short* o = (which == 0) ? o1 : (which == 1) ? o2 : oq;
    o[r] = f2b(W[k * D + n]);
}

// ---------------- MFMA GEMM: C[M,128] = A[M,128] @ W[128,128] (+bias) ----------------
// Swapped-operand mfma(w_frag, a_frag): lane&15 = C-row, 4 acc regs = 4 consecutive
// C-cols. Lane-strided direct stores would be ~8x write-amplified (R5: 116MB vs 13MB)
// so the epilogue round-trips through a PER-WAVE LDS patch (no barrier needed) and
// stores row-linear uint4: 4 consecutive lanes = 64B contiguous, full sectors.
// OUTF=0: bf16 out. OUTF=1: fp32 out + bias. Wave = 32 rows, block = 256 (128 rows).
template <int OUTF>
__global__ __launch_bounds__(256) void mfma_gemm(const float* __restrict__ Af,
                                                 const unsigned short* __restrict__ Ah,
                                                 const unsigned short* __restrict__ Al,
                                                 const unsigned short* __restrict__ Wth,
                                                 const float* __restrict__ bias,
                                                 unsigned short* __restrict__ Cb,
                                                 float* __restrict__ Cf, int M) {
    constexpr int RS = OUTF ? 136 : 68;           // LDS row stride (uints), 16B-aligned
    __shared__ unsigned int lds[4][16 * RS];
    int lane = threadIdx.x & 63;
    int wave = threadIdx.x >> 6;
    int m32 = (blockIdx.x * 4 + wave) * 32;
    if (m32 >= M) return;
    int mrow = lane & 15;
    int quad = lane >> 4;
    int nmt = (M - m32) >> 4;  // M % 16 == 0 always
    if (nmt > 2) nmt = 2;

    f32x4 acc[2][8];
#pragma unroll
    for (int mt = 0; mt < 2; ++mt)
#pragma unroll
        for (int nt = 0; nt < 8; ++nt) acc[mt][nt] = (f32x4){0.f, 0.f, 0.f, 0.f};

#pragma unroll
    for (int ks = 0; ks < 4; ++ks) {
        bf16x8 wf[8];
#pragma unroll
        for (int nt = 0; nt < 8; ++nt)
            wf[nt] = *(const bf16x8*)(Wth + (size_t)(nt * 16 + mrow) * D + ks * 32 + quad * 8);

        for (int mt = 0; mt < nmt; ++mt) {
            int arow = m32 + mt * 16 + mrow;
            bf16x8 ah, al;
            if (Af) {
                const float* ap = Af + (size_t)arow * D + ks * 32 + quad * 8;
                float4 v0 = *(const float4*)ap;
                float4 v1 = *(const float4*)(ap + 4);
                float vv[8] = {v0.x, v0.y, v0.z, v0.w, v1.x, v1.y, v1.z, v1.w};
#pragma unroll
                for (int j = 0; j < 8; ++j) {
                    unsigned short h = f2b(vv[j]);
                    ah[j] = (short)h;
                    al[j] = (short)f2b(vv[j] - b2f(h));
                }
            } else {
                ah = *(const bf16x8*)(Ah + (size_t)arow * D + ks * 32 + quad * 8);
                al = *(const bf16x8*)(Al + (size_t)arow * D + ks * 32 + quad * 8);
            }
#pragma unroll
            for (int nt = 0; nt < 8; ++nt) {
                acc[mt][nt] = __builtin_amdgcn_mfma_f32_16x16x32_bf16(wf[nt], ah, acc[mt][nt], 0, 0, 0);
                acc[mt][nt] = __builtin_amdgcn_mfma_f32_16x16x32_bf16(wf[nt], al, acc[mt][nt], 0, 0, 0);
            }
        }
    }

    // ---- epilogue: per-wave LDS transpose, then coalesced row-linear stores ----
    unsigned int* myl = lds[wave];
    int r = lane >> 2, qq = lane & 3;

    for (int mt = 0; mt < nmt; ++mt) {
        if (OUTF == 0) {
#pragma unroll
            for (int nt = 0; nt < 8; ++nt) {
                uint2 uu;
                uu.x = ((unsigned)f2b(acc[mt][nt][1]) << 16) | f2b(acc[mt][nt][0]);
                uu.y = ((unsigned)f2b(acc[mt][nt][3]) << 16) | f2b(acc[mt][nt][2]);
                *(uint2*)&myl[mrow * 68 + nt * 8 + quad * 2] = uu;
            }
            unsigned short* crow = Cb + (size_t)(m32 + mt * 16 + r) * D;
#pragma unroll
            for (int pass = 0; pass < 4; ++pass) {
                uint4 v = *(uint4*)&myl[r * 68 + qq * 4 + pass * 16];
                *(uint4*)(crow + (qq * 4 + pass * 16) * 2) = v;
            }
        } else {
#pragma unroll
            for (int nt = 0; nt < 8; ++nt) {
                float4 bv = ((const float4*)bias)[nt * 4 + quad];
                float4 o;
                o.x = acc[mt][nt][0] + bv.x;
                o.y = acc[mt][nt][1] + bv.y;
                o.z = acc[mt][nt][2] + bv.z;
                o.w = acc[mt][nt][3] + bv.w;
                *(float4*)&myl[mrow * 136 + nt * 16 + quad * 4] = o;
            }
            float* crow = Cf + (size_t)(m32 + mt * 16 + r) * D;
#pragma unroll
            for (int pass = 0; pass < 8; ++pass) {
                float4 v = *(float4*)&myl[r * 136 + qq * 4 + pass * 16];
                *(float4*)(crow + qq * 4 + pass * 16) = v;
            }
        }
    }
}

// ---------------- aggregation over bf16 rows ----------------
// O[i] = dinv[i] * sum_j w_j * T[j] + dinv[i]^2 * T[i] + b ; optional relu.
// T is bf16 [N,128]. mode 1: relu, write h1 as bf16 hi/lo. mode 0: write fp32.
__global__ __launch_bounds__(256) void aggregate(const unsigned short* __restrict__ Tb,
                                                 const int2* __restrict__ colvw,
                                                 const int* __restrict__ rs,
                                                 const float* __restrict__ dinv,
                                                 const float* __restrict__ bias,
                                                 float* __restrict__ Of,
                                                 unsigned short* __restrict__ Oh,
                                                 unsigned short* __restrict__ Ol,
                                                 int N, int mode) {
    int wave = threadIdx.x >> 6;
    int lane = threadIdx.x & 63;
    int i = blockIdx.x * 4 + wave;
    if (i >= N) return;

    const ushort2* T2 = (const ushort2*)Tb;
    int f = lane;  // ushort2 index within row (row = 64 ushort2 = 256B)

    int e0 = rs[i];
    int e1 = rs[i + 1];
    float ax = 0.f, ay = 0.f;

    for (int base = e0; base < e1; base += 64) {
        int cnt = e1 - base;
        if (cnt > 64) cnt = 64;
        int2 p = (lane < cnt) ? colvw[base + lane] : make_int2(0, 0);

        int t = 0;
        for (; t + 8 <= cnt; t += 8) {
            int jj[8];
            float ww[8];
#pragma unroll
            for (int k = 0; k < 8; ++k) {
                jj[k] = __shfl(p.x, t + k);
                ww[k] = __int_as_float(__shfl(p.y, t + k));
            }
            ushort2 rr[8];
#pragma unroll
            for (int k = 0; k < 8; ++k) rr[k] = T2[(size_t)jj[k] * 64 + f];
#pragma unroll
            for (int k = 0; k < 8; ++k) {
                ax = fmaf(ww[k], b2f(rr[k].x), ax);
                ay = fmaf(ww[k], b2f(rr[k].y), ay);
            }
        }
        for (; t < cnt; ++t) {
            int j = __shfl(p.x, t);
            float w = __int_as_float(__shfl(p.y, t));
            ushort2 r = T2[(size_t)j * 64 + f];
            ax = fmaf(w, b2f(r.x), ax);
            ay = fmaf(w, b2f(r.y), ay);
        }
    }

    float di = dinv[i];
    ushort2 selfr = T2[(size_t)i * 64 + f];
    float2 bv = ((const float2*)bias)[f];
    float rx = di * ax + di * di * b2f(selfr.x) + bv.x;
    float ry = di * ay + di * di * b2f(selfr.y) + bv.y;
    if (mode) {
        rx = fmaxf(rx, 0.f);
        ry = fmaxf(ry, 0.f);
        ushort2 h, l;
        h.x = f2b(rx); l.x = f2b(rx - b2f(h.x));
        h.y = f2b(ry); l.y = f2b(ry - b2f(h.y));
        ((ushort2*)Oh)[(size_t)i * 64 + f] = h;
        ((ushort2*)Ol)[(size_t)i * 64 + f] = l;
    } else {
        float2 res;
        res.x = rx;
        res.y = ry;
        ((float2*)Of)[(size_t)i * 64 + f] = res;
    }
}

// ---------------- launch ----------------

static inline char* carve(char*& w, size_t bytes) {
    char* p = w;
    w += (bytes + 255) & ~(size_t)255;
    return p;
}

extern "C" void kernel_launch(void* const* d_in, const int* in_sizes, int n_in,
                              void* d_out, int out_size, void* d_ws, size_t ws_size,
                              hipStream_t stream) {
    const float* x  = (const float*)d_in[0];
    const int*   ei = (const int*)d_in[1];
    const float* q  = (const float*)d_in[2];
    const float* W1 = (const float*)d_in[3];
    const float* b1 = (const float*)d_in[4];
    const float* W2 = (const float*)d_in[5];
    const float* b2 = (const float*)d_in[6];
    const float* Wq = (const float*)d_in[7];
    const float* bq = (const float*)d_in[8];

    int N  = in_sizes[0] / D;  // 50000
    int E  = in_sizes[1] / 2;  // 800000
    int MQ = in_sizes[2] / D;  // 20000

    const int* srcv = ei;
    const int* dstv = ei + E;

    char* w = (char*)d_ws;
    unsigned short* Cb   = (unsigned short*)carve(w, (size_t)N * D * 2);  // t1/t2 bf16
    unsigned short* Hb   = (unsigned short*)carve(w, (size_t)N * D * 2);  // h1-hi
    unsigned short* Lb   = (unsigned short*)carve(w, (size_t)N * D * 2);  // h1-lo
    int2*           colvw= (int2*)carve(w, (size_t)E * 8);
    int*            cnt  = (int*)carve(w, (size_t)N * 4);
    int*            rs   = (int*)carve(w, (size_t)(N + 1) * 4);
    int*            fp   = (int*)carve(w, (size_t)N * 4);
    float*          dinv = (float*)carve(w, (size_t)N * 4);
    int*            bsum = (int*)carve(w, 256 * 4);
    int*            boff = (int*)carve(w, 256 * 4);
    unsigned short* Wth1 = (unsigned short*)carve(w, D * D * 2);
    unsigned short* Wth2 = (unsigned short*)carve(w, D * D * 2);
    unsigned short* Wthq = (unsigned short*)carve(w, D * D * 2);

    float* outq = (float*)d_out;
    float* outh = outq + (size_t)MQ * D;

    int nb = (N + 1023) / 1024;  // 49

    // graph preprocessing
    hipMemsetAsync(cnt, 0, (size_t)N * 4, stream);
    hist_kernel<<<(E + 255) / 256, 256, 0, stream>>>(dstv, cnt, E);
    scan_phase1<<<nb, 256, 0, stream>>>(cnt, bsum, N);
    scan_phase2<<<1, 256, 0, stream>>>(bsum, boff, rs, nb, N);
    scan_phase3<<<nb, 256, 0, stream>>>(cnt, boff, rs, fp, dinv, N);
    fill_kernel<<<(E + 255) / 256, 256, 0, stream>>>(srcv, dstv, dinv, fp, colvw, E);

    wsplit3_kernel<<<192, 256, 0, stream>>>(W1, W2, Wq, Wth1, Wth2, Wthq);

    // conv1: t1 = x@W1 (bf16, in-kernel split) ; h1 = relu(agg(t1)+b1) -> bf16 hi/lo
    mfma_gemm<0><<<(N + 127) / 128, 256, 0, stream>>>(x, nullptr, nullptr, Wth1, nullptr, Cb, nullptr, N);
    aggregate<<<(N + 3) / 4, 256, 0, stream>>>(Cb, colvw, rs, dinv, b1, nullptr, Hb, Lb, N, 1);

    // conv2: t2 = h1@W2 (bf16) ; h2 = agg(t2)+b2 -> fp32 out
    mfma_gemm<0><<<(N + 127) / 128, 256, 0, stream>>>(nullptr, Hb, Lb, Wth2, nullptr, Cb, nullptr, N);
    aggregate<<<(N + 3) / 4, 256, 0, stream>>>(Cb, colvw, rs, dinv, b2, outh, nullptr, nullptr, N, 0);

    // ques = q@Wq + bq (fp32 out, in-kernel split)
    mfma_gemm<1><<<(MQ + 127) / 128, 256, 0, stream>>>(q, nullptr, nullptr, Wthq, bq, nullptr, outq, MQ);
}

// Round 7
// 310.845 us; speedup vs baseline: 1.2852x; 1.2852x over previous
//
#include <hip/hip_runtime.h>

#define D 128

typedef __attribute__((ext_vector_type(8))) short bf16x8;
typedef __attribute__((ext_vector_type(4))) float f32x4;

__device__ __forceinline__ unsigned short f2b(float v) {
    unsigned u = __float_as_uint(v);
    unsigned r = u + 0x7fffu + ((u >> 16) & 1u);   // RNE, inputs never NaN
    return (unsigned short)(r >> 16);
}
__device__ __forceinline__ float b2f(unsigned short h) {
    return __uint_as_float(((unsigned)h) << 16);
}

// ---------------- graph preprocessing ----------------

__global__ void hist_kernel(const int* __restrict__ dst, int* __restrict__ cnt, int E) {
    int e = blockIdx.x * blockDim.x + threadIdx.x;
    if (e < E) atomicAdd(&cnt[dst[e]], 1);
}

// ---- 3-phase multi-block exclusive scan over cnt[N] ----

__global__ __launch_bounds__(256) void scan_phase1(const int* __restrict__ cnt,
                                                   int* __restrict__ bsum, int N) {
    int t = threadIdx.x;
    int base = blockIdx.x * 1024 + t * 4;
    int s = 0;
    if (base + 4 <= N) {
        int4 v = *(const int4*)(cnt + base);
        s = v.x + v.y + v.z + v.w;
    } else {
        for (int k = 0; k < 4; ++k)
            if (base + k < N) s += cnt[base + k];
    }
    for (int off = 32; off; off >>= 1) s += __shfl_down(s, off);
    __shared__ int ws[4];
    if ((t & 63) == 0) ws[t >> 6] = s;
    __syncthreads();
    if (t == 0) bsum[blockIdx.x] = ws[0] + ws[1] + ws[2] + ws[3];
}

__global__ __launch_bounds__(256) void scan_phase2(const int* __restrict__ bsum,
                                                   int* __restrict__ boff,
                                                   int* __restrict__ rs, int nb, int N) {
    __shared__ int sh[256];
    int t = threadIdx.x;
    int v = (t < nb) ? bsum[t] : 0;
    sh[t] = v;
    __syncthreads();
    for (int off = 1; off < 256; off <<= 1) {
        int o = (t >= off) ? sh[t - off] : 0;
        __syncthreads();
        sh[t] += o;
        __syncthreads();
    }
    if (t < nb) boff[t] = sh[t] - v;
    if (t == 255) rs[N] = sh[255];  // == E
}

__global__ __launch_bounds__(256) void scan_phase3(const int* __restrict__ cnt,
                                                   const int* __restrict__ boff,
                                                   int* __restrict__ rs, int* __restrict__ fp,
                                                   float* __restrict__ dinv, int N) {
    __shared__ int tsum[256];
    int t = threadIdx.x;
    int base = blockIdx.x * 1024 + t * 4;
    int v[4];
    int s = 0;
    if (base + 4 <= N) {
        int4 vv = *(const int4*)(cnt + base);
        v[0] = vv.x; v[1] = vv.y; v[2] = vv.z; v[3] = vv.w;
        s = v[0] + v[1] + v[2] + v[3];
    } else {
        for (int k = 0; k < 4; ++k) {
            v[k] = (base + k < N) ? cnt[base + k] : 0;
            s += v[k];
        }
    }
    tsum[t] = s;
    __syncthreads();
    for (int off = 1; off < 256; off <<= 1) {
        int o = (t >= off) ? tsum[t - off] : 0;
        __syncthreads();
        tsum[t] += o;
        __syncthreads();
    }
    int run = boff[blockIdx.x] + tsum[t] - s;
#pragma unroll
    for (int k = 0; k < 4; ++k) {
        int idx = base + k;
        if (idx < N) {
            rs[idx] = run;
            fp[idx] = run;
            dinv[idx] = rsqrtf((float)(v[k] + 1));  // +1 self-loop
            run += v[k];
        }
    }
}

// CSR fill with packed (src, dinv[src]) payload -> one 8B scatter per edge
__global__ void fill_kernel(const int* __restrict__ src, const int* __restrict__ dst,
                            const float* __restrict__ dinv,
                            int* __restrict__ fp, int2* __restrict__ colvw, int E) {
    int e = blockIdx.x * blockDim.x + threadIdx.x;
    if (e < E) {
        int s = src[e];
        int slot = atomicAdd(&fp[dst[e]], 1);
        int2 p;
        p.x = s;
        p.y = __float_as_int(dinv[s]);
        colvw[slot] = p;
    }
}

// three W[128,128] fp32 -> bf16-hi transposed [n][k], one launch
__global__ void wsplit3_kernel(const float* __restrict__ W1, const float* __restrict__ W2,
                               const float* __restrict__ Wq,
                               unsigned short* __restrict__ o1, unsigned short* __restrict__ o2,
                               unsigned short* __restrict__ oq) {
    int t = blockIdx.x * blockDim.x + threadIdx.x;  // 3 * 16384
    int which = t >> 14;
    int r = t & 16383;
    int n = r >> 7, k = r & 127;
    const float* W = (which == 0) ? W1 : (which == 1) ? W2 : Wq;
    unsigned short* o = (which == 0) ? o1 : (which == 1) ? o2 : oq;
    o[r] = f2b(W[k * D + n]);
}

// ---------------- MFMA GEMM: C[M,128] = A[M,128] @ W[128,128] (+bias) ----------------
// r3-proven skeleton: mfma(a_frag, w_frag), C/D = col:lane&15 row:quad*4+reg.
// Wave = 16 rows, block = 256 (64 rows), grid (M+63)/64 -- 782 blocks at N=50000.
// Epilogue: per-wave LDS patch (scalar writes), then ROW-LINEAR whole-wave stores:
// 64 lanes x 4B (bf16) / 8B (fp32) = one full 256B/512B row per instruction --
// the exact store pattern that measured WRITE_SIZE == ideal in r3's aggregate.
// A: fp32 (in-kernel hi/lo split) or prescaled bf16 hi/lo. 2-term product.
template <int OUTF>
__global__ __launch_bounds__(256) void mfma_gemm(const float* __restrict__ Af,
                                                 const unsigned short* __restrict__ Ah,
                                                 const unsigned short* __restrict__ Al,
                                                 const unsigned short* __restrict__ Wth,
                                                 const float* __restrict__ bias,
                                                 unsigned short* __restrict__ Cb,
                                                 float* __restrict__ Cf, int M) {
    // per-wave patch: bf16 16 rows x 136 ushorts; fp32 16 rows x 132 floats
    __shared__ char smem[OUTF ? (4 * 16 * 132 * 4) : (4 * 16 * 136 * 2)];
    int lane = threadIdx.x & 63;
    int wave = threadIdx.x >> 6;
    int m16 = (blockIdx.x * 4 + wave) * 16;
    if (m16 >= M) return;
    int mrow = lane & 15;
    int quad = lane >> 4;

    f32x4 acc[8];
#pragma unroll
    for (int nt = 0; nt < 8; ++nt) acc[nt] = (f32x4){0.f, 0.f, 0.f, 0.f};

    int arow = m16 + mrow;

#pragma unroll
    for (int ks = 0; ks < 4; ++ks) {
        bf16x8 ah, al;
        if (Af) {
            const float* ap = Af + (size_t)arow * D + ks * 32 + quad * 8;
            float4 v0 = *(const float4*)ap;
            float4 v1 = *(const float4*)(ap + 4);
            float vv[8] = {v0.x, v0.y, v0.z, v0.w, v1.x, v1.y, v1.z, v1.w};
#pragma unroll
            for (int j = 0; j < 8; ++j) {
                unsigned short h = f2b(vv[j]);
                ah[j] = (short)h;
                al[j] = (short)f2b(vv[j] - b2f(h));
            }
        } else {
            ah = *(const bf16x8*)(Ah + (size_t)arow * D + ks * 32 + quad * 8);
            al = *(const bf16x8*)(Al + (size_t)arow * D + ks * 32 + quad * 8);
        }
#pragma unroll
        for (int nt = 0; nt < 8; ++nt) {
            bf16x8 wf = *(const bf16x8*)(Wth + (size_t)(nt * 16 + mrow) * D + ks * 32 + quad * 8);
            acc[nt] = __builtin_amdgcn_mfma_f32_16x16x32_bf16(ah, wf, acc[nt], 0, 0, 0);
            acc[nt] = __builtin_amdgcn_mfma_f32_16x16x32_bf16(al, wf, acc[nt], 0, 0, 0);
        }
    }

    // ---- epilogue: scatter into per-wave LDS patch, read back row-linear ----
    if (OUTF == 0) {
        unsigned short* myl = (unsigned short*)smem + wave * 16 * 136;
#pragma unroll
        for (int nt = 0; nt < 8; ++nt) {
            int col = nt * 16 + mrow;
#pragma unroll
            for (int r = 0; r < 4; ++r)
                myl[(quad * 4 + r) * 136 + col] = f2b(acc[nt][r]);
        }
        // 64 lanes x 4B = full 256B row per instruction
#pragma unroll
        for (int R = 0; R < 16; ++R) {
            unsigned int v = *(const unsigned int*)&myl[R * 136 + lane * 2];
            ((unsigned int*)(Cb + (size_t)(m16 + R) * D))[lane] = v;
        }
    } else {
        float* myl = (float*)smem + wave * 16 * 132;
#pragma unroll
        for (int nt = 0; nt < 8; ++nt) {
            int col = nt * 16 + mrow;
            float bv = bias[col];
#pragma unroll
            for (int r = 0; r < 4; ++r)
                myl[(quad * 4 + r) * 132 + col] = acc[nt][r] + bv;
        }
        // 64 lanes x 8B = full 512B row per instruction
#pragma unroll
        for (int R = 0; R < 16; ++R) {
            float2 v = *(const float2*)&myl[R * 132 + lane * 2];
            ((float2*)(Cf + (size_t)(m16 + R) * D))[lane] = v;
        }
    }
}

// ---------------- aggregation over bf16 rows ----------------
// O[i] = dinv[i] * sum_j w_j * T[j] + dinv[i]^2 * T[i] + b ; optional relu.
// T is bf16 [N,128]. mode 1: relu, write h1 as bf16 hi/lo. mode 0: write fp32.
__global__ __launch_bounds__(256) void aggregate(const unsigned short* __restrict__ Tb,
                                                 const int2* __restrict__ colvw,
                                                 const int* __restrict__ rs,
                                                 const float* __restrict__ dinv,
                                                 const float* __restrict__ bias,
                                                 float* __restrict__ Of,
                                                 unsigned short* __restrict__ Oh,
                                                 unsigned short* __restrict__ Ol,
                                                 int N, int mode) {
    int wave = threadIdx.x >> 6;
    int lane = threadIdx.x & 63;
    int i = blockIdx.x * 4 + wave;
    if (i >= N) return;

    const ushort2* T2 = (const ushort2*)Tb;
    int f = lane;  // ushort2 index within row (row = 64 ushort2 = 256B)

    int e0 = rs[i];
    int e1 = rs[i + 1];
    float ax = 0.f, ay = 0.f;

    for (int base = e0; base < e1; base += 64) {
        int cnt = e1 - base;
        if (cnt > 64) cnt = 64;
        int2 p = (lane < cnt) ? colvw[base + lane] : make_int2(0, 0);

        int t = 0;
        for (; t + 8 <= cnt; t += 8) {
            int jj[8];
            float ww[8];
#pragma unroll
            for (int k = 0; k < 8; ++k) {
                jj[k] = __shfl(p.x, t + k);
                ww[k] = __int_as_float(__shfl(p.y, t + k));
            }
            ushort2 rr[8];
#pragma unroll
            for (int k = 0; k < 8; ++k) rr[k] = T2[(size_t)jj[k] * 64 + f];
#pragma unroll
            for (int k = 0; k < 8; ++k) {
                ax = fmaf(ww[k], b2f(rr[k].x), ax);
                ay = fmaf(ww[k], b2f(rr[k].y), ay);
            }
        }
        for (; t < cnt; ++t) {
            int j = __shfl(p.x, t);
            float w = __int_as_float(__shfl(p.y, t));
            ushort2 r = T2[(size_t)j * 64 + f];
            ax = fmaf(w, b2f(r.x), ax);
            ay = fmaf(w, b2f(r.y), ay);
        }
    }

    float di = dinv[i];
    ushort2 selfr = T2[(size_t)i * 64 + f];
    float2 bv = ((const float2*)bias)[f];
    float rx = di * ax + di * di * b2f(selfr.x) + bv.x;
    float ry = di * ay + di * di * b2f(selfr.y) + bv.y;
    if (mode) {
        rx = fmaxf(rx, 0.f);
        ry = fmaxf(ry, 0.f);
        ushort2 h, l;
        h.x = f2b(rx); l.x = f2b(rx - b2f(h.x));
        h.y = f2b(ry); l.y = f2b(ry - b2f(h.y));
        ((ushort2*)Oh)[(size_t)i * 64 + f] = h;
        ((ushort2*)Ol)[(size_t)i * 64 + f] = l;
    } else {
        float2 res;
        res.x = rx;
        res.y = ry;
        ((float2*)Of)[(size_t)i * 64 + f] = res;
    }
}

// ---------------- launch ----------------

static inline char* carve(char*& w, size_t bytes) {
    char* p = w;
    w += (bytes + 255) & ~(size_t)255;
    return p;
}

extern "C" void kernel_launch(void* const* d_in, const int* in_sizes, int n_in,
                              void* d_out, int out_size, void* d_ws, size_t ws_size,
                              hipStream_t stream) {
    const float* x  = (const float*)d_in[0];
    const int*   ei = (const int*)d_in[1];
    const float* q  = (const float*)d_in[2];
    const float* W1 = (const float*)d_in[3];
    const float* b1 = (const float*)d_in[4];
    const float* W2 = (const float*)d_in[5];
    const float* b2 = (const float*)d_in[6];
    const float* Wq = (const float*)d_in[7];
    const float* bq = (const float*)d_in[8];

    int N  = in_sizes[0] / D;  // 50000
    int E  = in_sizes[1] / 2;  // 800000
    int MQ = in_sizes[2] / D;  // 20000

    const int* srcv = ei;
    const int* dstv = ei + E;

    char* w = (char*)d_ws;
    unsigned short* Cb   = (unsigned short*)carve(w, (size_t)N * D * 2);  // t1/t2 bf16
    unsigned short* Hb   = (unsigned short*)carve(w, (size_t)N * D * 2);  // h1-hi
    unsigned short* Lb   = (unsigned short*)carve(w, (size_t)N * D * 2);  // h1-lo
    int2*           colvw= (int2*)carve(w, (size_t)E * 8);
    int*            cnt  = (int*)carve(w, (size_t)N * 4);
    int*            rs   = (int*)carve(w, (size_t)(N + 1) * 4);
    int*            fp   = (int*)carve(w, (size_t)N * 4);
    float*          dinv = (float*)carve(w, (size_t)N * 4);
    int*            bsum = (int*)carve(w, 256 * 4);
    int*            boff = (int*)carve(w, 256 * 4);
    unsigned short* Wth1 = (unsigned short*)carve(w, D * D * 2);
    unsigned short* Wth2 = (unsigned short*)carve(w, D * D * 2);
    unsigned short* Wthq = (unsigned short*)carve(w, D * D * 2);

    float* outq = (float*)d_out;
    float* outh = outq + (size_t)MQ * D;

    int nb = (N + 1023) / 1024;  // 49

    // graph preprocessing
    hipMemsetAsync(cnt, 0, (size_t)N * 4, stream);
    hist_kernel<<<(E + 255) / 256, 256, 0, stream>>>(dstv, cnt, E);
    scan_phase1<<<nb, 256, 0, stream>>>(cnt, bsum, N);
    scan_phase2<<<1, 256, 0, stream>>>(bsum, boff, rs, nb, N);
    scan_phase3<<<nb, 256, 0, stream>>>(cnt, boff, rs, fp, dinv, N);
    fill_kernel<<<(E + 255) / 256, 256, 0, stream>>>(srcv, dstv, dinv, fp, colvw, E);

    wsplit3_kernel<<<192, 256, 0, stream>>>(W1, W2, Wq, Wth1, Wth2, Wthq);

    // conv1: t1 = x@W1 (bf16, in-kernel split) ; h1 = relu(agg(t1)+b1) -> bf16 hi/lo
    mfma_gemm<0><<<(N + 63) / 64, 256, 0, stream>>>(x, nullptr, nullptr, Wth1, nullptr, Cb, nullptr, N);
    aggregate<<<(N + 3) / 4, 256, 0, stream>>>(Cb, colvw, rs, dinv, b1, nullptr, Hb, Lb, N, 1);

    // conv2: t2 = h1@W2 (bf16) ; h2 = agg(t2)+b2 -> fp32 out
    mfma_gemm<0><<<(N + 63) / 64, 256, 0, stream>>>(nullptr, Hb, Lb, Wth2, nullptr, Cb, nullptr, N);
    aggregate<<<(N + 3) / 4, 256, 0, stream>>>(Cb, colvw, rs, dinv, b2, outh, nullptr, nullptr, N, 0);

    // ques = q@Wq + bq (fp32 out, in-kernel split)
    mfma_gemm<1><<<(MQ + 63) / 64, 256, 0, stream>>>(q, nullptr, nullptr, Wthq, bq, nullptr, outq, MQ);
}

// Round 8
// 304.250 us; speedup vs baseline: 1.3131x; 1.0217x over previous
//
#include <hip/hip_runtime.h>

#define D 128
#define NS 8  // CSR-fill slices == XCD count

typedef __attribute__((ext_vector_type(8))) short bf16x8;
typedef __attribute__((ext_vector_type(4))) float f32x4;

__device__ __forceinline__ unsigned short f2b(float v) {
    unsigned u = __float_as_uint(v);
    unsigned r = u + 0x7fffu + ((u >> 16) & 1u);   // RNE, inputs never NaN
    return (unsigned short)(r >> 16);
}
__device__ __forceinline__ float b2f(unsigned short h) {
    return __uint_as_float(((unsigned)h) << 16);
}

// ---------------- graph preprocessing ----------------

__global__ void hist_kernel(const int* __restrict__ dst, int* __restrict__ cnt, int E) {
    int e = blockIdx.x * blockDim.x + threadIdx.x;
    if (e < E) atomicAdd(&cnt[dst[e]], 1);
}

// ---- 3-phase multi-block exclusive scan over cnt[N] ----

__global__ __launch_bounds__(256) void scan_phase1(const int* __restrict__ cnt,
                                                   int* __restrict__ bsum, int N) {
    int t = threadIdx.x;
    int base = blockIdx.x * 1024 + t * 4;
    int s = 0;
    if (base + 4 <= N) {
        int4 v = *(const int4*)(cnt + base);
        s = v.x + v.y + v.z + v.w;
    } else {
        for (int k = 0; k < 4; ++k)
            if (base + k < N) s += cnt[base + k];
    }
    for (int off = 32; off; off >>= 1) s += __shfl_down(s, off);
    __shared__ int ws[4];
    if ((t & 63) == 0) ws[t >> 6] = s;
    __syncthreads();
    if (t == 0) bsum[blockIdx.x] = ws[0] + ws[1] + ws[2] + ws[3];
}

__global__ __launch_bounds__(256) void scan_phase2(const int* __restrict__ bsum,
                                                   int* __restrict__ boff,
                                                   int* __restrict__ rs, int nb, int N) {
    __shared__ int sh[256];
    int t = threadIdx.x;
    int v = (t < nb) ? bsum[t] : 0;
    sh[t] = v;
    __syncthreads();
    for (int off = 1; off < 256; off <<= 1) {
        int o = (t >= off) ? sh[t - off] : 0;
        __syncthreads();
        sh[t] += o;
        __syncthreads();
    }
    if (t < nb) boff[t] = sh[t] - v;
    if (t == 255) rs[N] = sh[255];  // == E
}

__global__ __launch_bounds__(256) void scan_phase3(const int* __restrict__ cnt,
                                                   const int* __restrict__ boff,
                                                   int* __restrict__ rs, int* __restrict__ fp,
                                                   float* __restrict__ dinv, int N) {
    __shared__ int tsum[256];
    int t = threadIdx.x;
    int base = blockIdx.x * 1024 + t * 4;
    int v[4];
    int s = 0;
    if (base + 4 <= N) {
        int4 vv = *(const int4*)(cnt + base);
        v[0] = vv.x; v[1] = vv.y; v[2] = vv.z; v[3] = vv.w;
        s = v[0] + v[1] + v[2] + v[3];
    } else {
        for (int k = 0; k < 4; ++k) {
            v[k] = (base + k < N) ? cnt[base + k] : 0;
            s += v[k];
        }
    }
    tsum[t] = s;
    __syncthreads();
    for (int off = 1; off < 256; off <<= 1) {
        int o = (t >= off) ? tsum[t - off] : 0;
        __syncthreads();
        tsum[t] += o;
        __syncthreads();
    }
    int run = boff[blockIdx.x] + tsum[t] - s;
#pragma unroll
    for (int k = 0; k < 4; ++k) {
        int idx = base + k;
        if (idx < N) {
            rs[idx] = run;
            fp[idx] = run;
            dinv[idx] = rsqrtf((float)(v[k] + 1));  // +1 self-loop
            run += v[k];
        }
    }
}

// Sliced CSR fill: slice s = blockIdx&7 handles dst in [s*nps, (s+1)*nps).
// Each slice's colvw target range is contiguous (~0.8MB) and written only by
// that slice's blocks -> (XCD %8 swizzle heuristic) writes coalesce in one
// XCD's L2 instead of one 64B line-writeback per edge (r7: WRITE 52.7MB vs
// 6.4MB ideal). dst re-read NS times but is 3.2MB = L2/L3-resident.
__global__ __launch_bounds__(256) void fill_sliced(const int* __restrict__ src,
                                                   const int* __restrict__ dst,
                                                   const float* __restrict__ dinv,
                                                   int* __restrict__ fp,
                                                   int2* __restrict__ colvw,
                                                   int E, int nps) {
    int s = blockIdx.x & (NS - 1);
    int chunk = blockIdx.x >> 3;
    int nchunks = gridDim.x >> 3;
    int lo = s * nps, hi = lo + nps;
    int stride = nchunks * blockDim.x;
    for (int e = chunk * blockDim.x + threadIdx.x; e < E; e += stride) {
        int d = dst[e];
        if (d >= lo && d < hi) {
            int sv = src[e];
            int slot = atomicAdd(&fp[d], 1);
            int2 p;
            p.x = sv;
            p.y = __float_as_int(dinv[sv]);
            colvw[slot] = p;
        }
    }
}

// three W[128,128] fp32 -> bf16-hi transposed [n][k], one launch
__global__ void wsplit3_kernel(const float* __restrict__ W1, const float* __restrict__ W2,
                               const float* __restrict__ Wq,
                               unsigned short* __restrict__ o1, unsigned short* __restrict__ o2,
                               unsigned short* __restrict__ oq) {
    int t = blockIdx.x * blockDim.x + threadIdx.x;  // 3 * 16384
    int which = t >> 14;
    int r = t & 16383;
    int n = r >> 7, k = r & 127;
    const float* W = (which == 0) ? W1 : (which == 1) ? W2 : Wq;
    unsigned short* o = (which == 0) ? o1 : (which == 1) ? o2 : oq;
    o[r] = f2b(W[k * D + n]);
}

// ---------------- MFMA GEMM: C[M,128] = A[M,128] @ W[128,128] (+bias) ----------------
// r3-proven skeleton: mfma(a_frag, w_frag), C/D = col:lane&15 row:quad*4+reg.
// Wave = 16 rows, block = 256 (64 rows). Epilogue: per-wave LDS patch, then
// row-linear whole-wave stores (64 lanes cover a full row) -- WRITE-exact (r7).
template <int OUTF>
__global__ __launch_bounds__(256) void mfma_gemm(const float* __restrict__ Af,
                                                 const unsigned short* __restrict__ Ah,
                                                 const unsigned short* __restrict__ Al,
                                                 const unsigned short* __restrict__ Wth,
                                                 const float* __restrict__ bias,
                                                 unsigned short* __restrict__ Cb,
                                                 float* __restrict__ Cf, int M) {
    __shared__ char smem[OUTF ? (4 * 16 * 132 * 4) : (4 * 16 * 136 * 2)];
    int lane = threadIdx.x & 63;
    int wave = threadIdx.x >> 6;
    int m16 = (blockIdx.x * 4 + wave) * 16;
    if (m16 >= M) return;
    int mrow = lane & 15;
    int quad = lane >> 4;

    f32x4 acc[8];
#pragma unroll
    for (int nt = 0; nt < 8; ++nt) acc[nt] = (f32x4){0.f, 0.f, 0.f, 0.f};

    int arow = m16 + mrow;

#pragma unroll
    for (int ks = 0; ks < 4; ++ks) {
        bf16x8 ah, al;
        if (Af) {
            const float* ap = Af + (size_t)arow * D + ks * 32 + quad * 8;
            float4 v0 = *(const float4*)ap;
            float4 v1 = *(const float4*)(ap + 4);
            float vv[8] = {v0.x, v0.y, v0.z, v0.w, v1.x, v1.y, v1.z, v1.w};
#pragma unroll
            for (int j = 0; j < 8; ++j) {
                unsigned short h = f2b(vv[j]);
                ah[j] = (short)h;
                al[j] = (short)f2b(vv[j] - b2f(h));
            }
        } else {
            ah = *(const bf16x8*)(Ah + (size_t)arow * D + ks * 32 + quad * 8);
            al = *(const bf16x8*)(Al + (size_t)arow * D + ks * 32 + quad * 8);
        }
#pragma unroll
        for (int nt = 0; nt < 8; ++nt) {
            bf16x8 wf = *(const bf16x8*)(Wth + (size_t)(nt * 16 + mrow) * D + ks * 32 + quad * 8);
            acc[nt] = __builtin_amdgcn_mfma_f32_16x16x32_bf16(ah, wf, acc[nt], 0, 0, 0);
            acc[nt] = __builtin_amdgcn_mfma_f32_16x16x32_bf16(al, wf, acc[nt], 0, 0, 0);
        }
    }

    if (OUTF == 0) {
        unsigned short* myl = (unsigned short*)smem + wave * 16 * 136;
#pragma unroll
        for (int nt = 0; nt < 8; ++nt) {
            int col = nt * 16 + mrow;
#pragma unroll
            for (int r = 0; r < 4; ++r)
                myl[(quad * 4 + r) * 136 + col] = f2b(acc[nt][r]);
        }
#pragma unroll
        for (int R = 0; R < 16; ++R) {
            unsigned int v = *(const unsigned int*)&myl[R * 136 + lane * 2];
            ((unsigned int*)(Cb + (size_t)(m16 + R) * D))[lane] = v;
        }
    } else {
        float* myl = (float*)smem + wave * 16 * 132;
#pragma unroll
        for (int nt = 0; nt < 8; ++nt) {
            int col = nt * 16 + mrow;
            float bv = bias[col];
#pragma unroll
            for (int r = 0; r < 4; ++r)
                myl[(quad * 4 + r) * 132 + col] = acc[nt][r] + bv;
        }
#pragma unroll
        for (int R = 0; R < 16; ++R) {
            float2 v = *(const float2*)&myl[R * 132 + lane * 2];
            ((float2*)(Cf + (size_t)(m16 + R) * D))[lane] = v;
        }
    }
}

// ---------------- aggregation over bf16 rows ----------------
// O[i] = dinv[i] * sum_j w_j * T[j] + dinv[i]^2 * T[i] + b ; optional relu.
// T is bf16 [N,128]. mode 1: relu, write h1 as bf16 hi/lo. mode 0: write fp32.
__global__ __launch_bounds__(256) void aggregate(const unsigned short* __restrict__ Tb,
                                                 const int2* __restrict__ colvw,
                                                 const int* __restrict__ rs,
                                                 const float* __restrict__ dinv,
                                                 const float* __restrict__ bias,
                                                 float* __restrict__ Of,
                                                 unsigned short* __restrict__ Oh,
                                                 unsigned short* __restrict__ Ol,
                                                 int N, int mode) {
    int wave = threadIdx.x >> 6;
    int lane = threadIdx.x & 63;
    int i = blockIdx.x * 4 + wave;
    if (i >= N) return;

    const ushort2* T2 = (const ushort2*)Tb;
    int f = lane;  // ushort2 index within row (row = 64 ushort2 = 256B)

    int e0 = rs[i];
    int e1 = rs[i + 1];
    float ax = 0.f, ay = 0.f;

    for (int base = e0; base < e1; base += 64) {
        int cnt = e1 - base;
        if (cnt > 64) cnt = 64;
        int2 p = (lane < cnt) ? colvw[base + lane] : make_int2(0, 0);

        int t = 0;
        for (; t + 8 <= cnt; t += 8) {
            int jj[8];
            float ww[8];
#pragma unroll
            for (int k = 0; k < 8; ++k) {
                jj[k] = __shfl(p.x, t + k);
                ww[k] = __int_as_float(__shfl(p.y, t + k));
            }
            ushort2 rr[8];
#pragma unroll
            for (int k = 0; k < 8; ++k) rr[k] = T2[(size_t)jj[k] * 64 + f];
#pragma unroll
            for (int k = 0; k < 8; ++k) {
                ax = fmaf(ww[k], b2f(rr[k].x), ax);
                ay = fmaf(ww[k], b2f(rr[k].y), ay);
            }
        }
        for (; t < cnt; ++t) {
            int j = __shfl(p.x, t);
            float w = __int_as_float(__shfl(p.y, t));
            ushort2 r = T2[(size_t)j * 64 + f];
            ax = fmaf(w, b2f(r.x), ax);
            ay = fmaf(w, b2f(r.y), ay);
        }
    }

    float di = dinv[i];
    ushort2 selfr = T2[(size_t)i * 64 + f];
    float2 bv = ((const float2*)bias)[f];
    float rx = di * ax + di * di * b2f(selfr.x) + bv.x;
    float ry = di * ay + di * di * b2f(selfr.y) + bv.y;
    if (mode) {
        rx = fmaxf(rx, 0.f);
        ry = fmaxf(ry, 0.f);
        ushort2 h, l;
        h.x = f2b(rx); l.x = f2b(rx - b2f(h.x));
        h.y = f2b(ry); l.y = f2b(ry - b2f(h.y));
        ((ushort2*)Oh)[(size_t)i * 64 + f] = h;
        ((ushort2*)Ol)[(size_t)i * 64 + f] = l;
    } else {
        float2 res;
        res.x = rx;
        res.y = ry;
        ((float2*)Of)[(size_t)i * 64 + f] = res;
    }
}

// ---------------- launch ----------------

static inline char* carve(char*& w, size_t bytes) {
    char* p = w;
    w += (bytes + 255) & ~(size_t)255;
    return p;
}

extern "C" void kernel_launch(void* const* d_in, const int* in_sizes, int n_in,
                              void* d_out, int out_size, void* d_ws, size_t ws_size,
                              hipStream_t stream) {
    const float* x  = (const float*)d_in[0];
    const int*   ei = (const int*)d_in[1];
    const float* q  = (const float*)d_in[2];
    const float* W1 = (const float*)d_in[3];
    const float* b1 = (const float*)d_in[4];
    const float* W2 = (const float*)d_in[5];
    const float* b2 = (const float*)d_in[6];
    const float* Wq = (const float*)d_in[7];
    const float* bq = (const float*)d_in[8];

    int N  = in_sizes[0] / D;  // 50000
    int E  = in_sizes[1] / 2;  // 800000
    int MQ = in_sizes[2] / D;  // 20000

    const int* srcv = ei;
    const int* dstv = ei + E;

    char* w = (char*)d_ws;
    unsigned short* Cb   = (unsigned short*)carve(w, (size_t)N * D * 2);  // t1/t2 bf16
    unsigned short* Hb   = (unsigned short*)carve(w, (size_t)N * D * 2);  // h1-hi
    unsigned short* Lb   = (unsigned short*)carve(w, (size_t)N * D * 2);  // h1-lo
    int2*           colvw= (int2*)carve(w, (size_t)E * 8);
    int*            cnt  = (int*)carve(w, (size_t)N * 4);
    int*            rs   = (int*)carve(w, (size_t)(N + 1) * 4);
    int*            fp   = (int*)carve(w, (size_t)N * 4);
    float*          dinv = (float*)carve(w, (size_t)N * 4);
    int*            bsum = (int*)carve(w, 256 * 4);
    int*            boff = (int*)carve(w, 256 * 4);
    unsigned short* Wth1 = (unsigned short*)carve(w, D * D * 2);
    unsigned short* Wth2 = (unsigned short*)carve(w, D * D * 2);
    unsigned short* Wthq = (unsigned short*)carve(w, D * D * 2);

    float* outq = (float*)d_out;
    float* outh = outq + (size_t)MQ * D;

    int nb = (N + 1023) / 1024;  // 49
    int nps = (N + NS - 1) / NS; // nodes per fill slice

    // graph preprocessing
    hipMemsetAsync(cnt, 0, (size_t)N * 4, stream);
    hist_kernel<<<(E + 255) / 256, 256, 0, stream>>>(dstv, cnt, E);
    scan_phase1<<<nb, 256, 0, stream>>>(cnt, bsum, N);
    scan_phase2<<<1, 256, 0, stream>>>(bsum, boff, rs, nb, N);
    scan_phase3<<<nb, 256, 0, stream>>>(cnt, boff, rs, fp, dinv, N);
    fill_sliced<<<128 * NS, 256, 0, stream>>>(srcv, dstv, dinv, fp, colvw, E, nps);

    wsplit3_kernel<<<192, 256, 0, stream>>>(W1, W2, Wq, Wth1, Wth2, Wthq);

    // conv1: t1 = x@W1 (bf16, in-kernel split) ; h1 = relu(agg(t1)+b1) -> bf16 hi/lo
    mfma_gemm<0><<<(N + 63) / 64, 256, 0, stream>>>(x, nullptr, nullptr, Wth1, nullptr, Cb, nullptr, N);
    aggregate<<<(N + 3) / 4, 256, 0, stream>>>(Cb, colvw, rs, dinv, b1, nullptr, Hb, Lb, N, 1);

    // conv2: t2 = h1@W2 (bf16) ; h2 = agg(t2)+b2 -> fp32 out
    mfma_gemm<0><<<(N + 63) / 64, 256, 0, stream>>>(nullptr, Hb, Lb, Wth2, nullptr, Cb, nullptr, N);
    aggregate<<<(N + 3) / 4, 256, 0, stream>>>(Cb, colvw, rs, dinv, b2, outh, nullptr, nullptr, N, 0);

    // ques = q@Wq + bq (fp32 out, in-kernel split)
    mfma_gemm<1><<<(MQ + 63) / 64, 256, 0, stream>>>(q, nullptr, nullptr, Wthq, bq, nullptr, outq, MQ);
}

// Round 9
// 297.332 us; speedup vs baseline: 1.3437x; 1.0233x over previous
//
#include <hip/hip_runtime.h>

#define D 128
#define NS 8  // CSR-fill slices == XCD count

typedef __attribute__((ext_vector_type(8))) short bf16x8;
typedef __attribute__((ext_vector_type(4))) float f32x4;

__device__ __forceinline__ unsigned short f2b(float v) {
    unsigned u = __float_as_uint(v);
    unsigned r = u + 0x7fffu + ((u >> 16) & 1u);   // RNE, inputs never NaN
    return (unsigned short)(r >> 16);
}
__device__ __forceinline__ float b2f(unsigned short h) {
    return __uint_as_float(((unsigned)h) << 16);
}

// ---------------- graph preprocessing ----------------

__global__ void hist_kernel(const int* __restrict__ dst, int* __restrict__ cnt, int E) {
    int e = blockIdx.x * blockDim.x + threadIdx.x;
    if (e < E) atomicAdd(&cnt[dst[e]], 1);
}

// ---- scan phase1 fused with the 3x weight transpose+convert (independent work) ----
// blocks [0, nb): per-block sums of cnt. blocks [nb, nb+192): Wt bf16 convert.

__global__ __launch_bounds__(256) void scan1_wsplit(const int* __restrict__ cnt,
                                                    int* __restrict__ bsum, int N, int nb,
                                                    const float* __restrict__ W1,
                                                    const float* __restrict__ W2,
                                                    const float* __restrict__ Wq,
                                                    unsigned short* __restrict__ o1,
                                                    unsigned short* __restrict__ o2,
                                                    unsigned short* __restrict__ oq) {
    int b = blockIdx.x;
    if (b >= nb) {
        int t = (b - nb) * 256 + threadIdx.x;  // 3 * 16384
        int which = t >> 14;
        int r = t & 16383;
        int n = r >> 7, k = r & 127;
        const float* W = (which == 0) ? W1 : (which == 1) ? W2 : Wq;
        unsigned short* o = (which == 0) ? o1 : (which == 1) ? o2 : oq;
        o[r] = f2b(W[k * D + n]);
        return;
    }
    int t = threadIdx.x;
    int base = b * 1024 + t * 4;
    int s = 0;
    if (base + 4 <= N) {
        int4 v = *(const int4*)(cnt + base);
        s = v.x + v.y + v.z + v.w;
    } else {
        for (int k = 0; k < 4; ++k)
            if (base + k < N) s += cnt[base + k];
    }
    for (int off = 32; off; off >>= 1) s += __shfl_down(s, off);
    __shared__ int ws[4];
    if ((t & 63) == 0) ws[t >> 6] = s;
    __syncthreads();
    if (t == 0) bsum[b] = ws[0] + ws[1] + ws[2] + ws[3];
}

__global__ __launch_bounds__(256) void scan_phase2(const int* __restrict__ bsum,
                                                   int* __restrict__ boff,
                                                   int* __restrict__ rs, int nb, int N) {
    __shared__ int sh[256];
    int t = threadIdx.x;
    int v = (t < nb) ? bsum[t] : 0;
    sh[t] = v;
    __syncthreads();
    for (int off = 1; off < 256; off <<= 1) {
        int o = (t >= off) ? sh[t - off] : 0;
        __syncthreads();
        sh[t] += o;
        __syncthreads();
    }
    if (t < nb) boff[t] = sh[t] - v;
    if (t == 255) rs[N] = sh[255];  // == E
}

__global__ __launch_bounds__(256) void scan_phase3(const int* __restrict__ cnt,
                                                   const int* __restrict__ boff,
                                                   int* __restrict__ rs, int* __restrict__ fp,
                                                   float* __restrict__ dinv, int N) {
    __shared__ int tsum[256];
    int t = threadIdx.x;
    int base = blockIdx.x * 1024 + t * 4;
    int v[4];
    int s = 0;
    if (base + 4 <= N) {
        int4 vv = *(const int4*)(cnt + base);
        v[0] = vv.x; v[1] = vv.y; v[2] = vv.z; v[3] = vv.w;
        s = v[0] + v[1] + v[2] + v[3];
    } else {
        for (int k = 0; k < 4; ++k) {
            v[k] = (base + k < N) ? cnt[base + k] : 0;
            s += v[k];
        }
    }
    tsum[t] = s;
    __syncthreads();
    for (int off = 1; off < 256; off <<= 1) {
        int o = (t >= off) ? tsum[t - off] : 0;
        __syncthreads();
        tsum[t] += o;
        __syncthreads();
    }
    int run = boff[blockIdx.x] + tsum[t] - s;
#pragma unroll
    for (int k = 0; k < 4; ++k) {
        int idx = base + k;
        if (idx < N) {
            rs[idx] = run;
            fp[idx] = run;
            dinv[idx] = rsqrtf((float)(v[k] + 1));  // +1 self-loop
            run += v[k];
        }
    }
}

// Sliced CSR fill, 4B payload (src only; dinv looked up in aggregate from the
// L2-hot 200KB table). Slice s = blockIdx&7 handles dst in [s*nps,(s+1)*nps):
// contiguous ~0.4MB colv target range per slice.
__global__ __launch_bounds__(256) void fill_sliced(const int* __restrict__ src,
                                                   const int* __restrict__ dst,
                                                   int* __restrict__ fp,
                                                   int* __restrict__ colv,
                                                   int E, int nps) {
    int s = blockIdx.x & (NS - 1);
    int chunk = blockIdx.x >> 3;
    int nchunks = gridDim.x >> 3;
    int lo = s * nps, hi = lo + nps;
    int stride = nchunks * blockDim.x;
    for (int e = chunk * blockDim.x + threadIdx.x; e < E; e += stride) {
        int d = dst[e];
        if (d >= lo && d < hi) {
            int slot = atomicAdd(&fp[d], 1);
            colv[slot] = src[e];
        }
    }
}

// ---------------- MFMA GEMM bodies ----------------
// r7-proven skeleton: mfma(a_frag, w_frag), C/D = col:lane&15 row:quad*4+reg.
// Wave = 16 rows, 4 waves/block. Epilogue: per-wave LDS patch -> row-linear
// whole-wave stores (64 lanes cover a full row) -- WRITE-exact (r7).

__device__ __forceinline__ void gemm_body(const float* Af, const unsigned short* Ah,
                                          const unsigned short* Al,
                                          const unsigned short* __restrict__ Wth,
                                          const float* bias, unsigned short* Cb,
                                          float* Cf, int M, int bid, int outf,
                                          char* smem) {
    int lane = threadIdx.x & 63;
    int wave = threadIdx.x >> 6;
    int m16 = (bid * 4 + wave) * 16;
    if (m16 >= M) return;
    int mrow = lane & 15;
    int quad = lane >> 4;

    f32x4 acc[8];
#pragma unroll
    for (int nt = 0; nt < 8; ++nt) acc[nt] = (f32x4){0.f, 0.f, 0.f, 0.f};

    int arow = m16 + mrow;

#pragma unroll
    for (int ks = 0; ks < 4; ++ks) {
        bf16x8 ah, al;
        if (Af) {
            const float* ap = Af + (size_t)arow * D + ks * 32 + quad * 8;
            float4 v0 = *(const float4*)ap;
            float4 v1 = *(const float4*)(ap + 4);
            float vv[8] = {v0.x, v0.y, v0.z, v0.w, v1.x, v1.y, v1.z, v1.w};
#pragma unroll
            for (int j = 0; j < 8; ++j) {
                unsigned short h = f2b(vv[j]);
                ah[j] = (short)h;
                al[j] = (short)f2b(vv[j] - b2f(h));
            }
        } else {
            ah = *(const bf16x8*)(Ah + (size_t)arow * D + ks * 32 + quad * 8);
            al = *(const bf16x8*)(Al + (size_t)arow * D + ks * 32 + quad * 8);
        }
#pragma unroll
        for (int nt = 0; nt < 8; ++nt) {
            bf16x8 wf = *(const bf16x8*)(Wth + (size_t)(nt * 16 + mrow) * D + ks * 32 + quad * 8);
            acc[nt] = __builtin_amdgcn_mfma_f32_16x16x32_bf16(ah, wf, acc[nt], 0, 0, 0);
            acc[nt] = __builtin_amdgcn_mfma_f32_16x16x32_bf16(al, wf, acc[nt], 0, 0, 0);
        }
    }

    if (outf == 0) {
        unsigned short* myl = (unsigned short*)smem + wave * 16 * 136;
#pragma unroll
        for (int nt = 0; nt < 8; ++nt) {
            int col = nt * 16 + mrow;
#pragma unroll
            for (int r = 0; r < 4; ++r)
                myl[(quad * 4 + r) * 136 + col] = f2b(acc[nt][r]);
        }
#pragma unroll
        for (int R = 0; R < 16; ++R) {
            unsigned int v = *(const unsigned int*)&myl[R * 136 + lane * 2];
            ((unsigned int*)(Cb + (size_t)(m16 + R) * D))[lane] = v;
        }
    } else {
        float* myl = (float*)smem + wave * 16 * 132;
#pragma unroll
        for (int nt = 0; nt < 8; ++nt) {
            int col = nt * 16 + mrow;
            float bv = bias[col];
#pragma unroll
            for (int r = 0; r < 4; ++r)
                myl[(quad * 4 + r) * 132 + col] = acc[nt][r] + bv;
        }
#pragma unroll
        for (int R = 0; R < 16; ++R) {
            float2 v = *(const float2*)&myl[R * 132 + lane * 2];
            ((float2*)(Cf + (size_t)(m16 + R) * D))[lane] = v;
        }
    }
}

// Fused conv1 + ques GEMM: blocks [0,nbN) do t1 = x@W1 -> bf16 Cb;
// blocks [nbN, nbN+nbQ) do ques = q@Wq + bq -> fp32 outq.
__global__ __launch_bounds__(256) void gemm1q(const float* __restrict__ x,
                                              const float* __restrict__ q,
                                              const unsigned short* __restrict__ Wth1,
                                              const unsigned short* __restrict__ Wthq,
                                              const float* __restrict__ bq,
                                              unsigned short* __restrict__ Cb,
                                              float* __restrict__ outq,
                                              int N, int MQ, int nbN) {
    __shared__ char smem[4 * 16 * 132 * 4];
    int b = blockIdx.x;
    if (b < nbN)
        gemm_body(x, nullptr, nullptr, Wth1, nullptr, Cb, nullptr, N, b, 0, smem);
    else
        gemm_body(q, nullptr, nullptr, Wthq, bq, nullptr, outq, MQ, b - nbN, 1, smem);
}

// conv2 GEMM: t2 = (Hb+Lb)@W2 -> bf16 Cb
__global__ __launch_bounds__(256) void gemm2(const unsigned short* __restrict__ Ah,
                                             const unsigned short* __restrict__ Al,
                                             const unsigned short* __restrict__ Wth,
                                             unsigned short* __restrict__ Cb, int M) {
    __shared__ char smem[4 * 16 * 136 * 2];
    gemm_body(nullptr, Ah, Al, Wth, nullptr, Cb, nullptr, M, blockIdx.x, 0, smem);
}

// ---------------- aggregation over bf16 rows ----------------
// O[i] = dinv[i] * sum_j dinv[j] * T[j] + dinv[i]^2 * T[i] + b ; optional relu.
// 512 thr = 8 waves = 8 nodes/block (more resident waves to hide gather latency).
// dinv[j] fetched at prefetch time from the L2-hot 200KB table.
__global__ __launch_bounds__(512) void aggregate(const unsigned short* __restrict__ Tb,
                                                 const int* __restrict__ colv,
                                                 const int* __restrict__ rs,
                                                 const float* __restrict__ dinv,
                                                 const float* __restrict__ bias,
                                                 float* __restrict__ Of,
                                                 unsigned short* __restrict__ Oh,
                                                 unsigned short* __restrict__ Ol,
                                                 int N, int mode) {
    int wave = threadIdx.x >> 6;
    int lane = threadIdx.x & 63;
    int i = blockIdx.x * 8 + wave;
    if (i >= N) return;

    const ushort2* T2 = (const ushort2*)Tb;
    int f = lane;  // ushort2 index within row (row = 64 ushort2 = 256B)

    int e0 = rs[i];
    int e1 = rs[i + 1];
    float ax = 0.f, ay = 0.f;

    for (int base = e0; base < e1; base += 64) {
        int cnt = e1 - base;
        if (cnt > 64) cnt = 64;
        int jv = (lane < cnt) ? colv[base + lane] : 0;
        float wv = dinv[jv];

        int t = 0;
        for (; t + 8 <= cnt; t += 8) {
            int jj[8];
            float ww[8];
#pragma unroll
            for (int k = 0; k < 8; ++k) {
                jj[k] = __shfl(jv, t + k);
                ww[k] = __shfl(wv, t + k);
            }
            ushort2 rr[8];
#pragma unroll
            for (int k = 0; k < 8; ++k) rr[k] = T2[(size_t)jj[k] * 64 + f];
#pragma unroll
            for (int k = 0; k < 8; ++k) {
                ax = fmaf(ww[k], b2f(rr[k].x), ax);
                ay = fmaf(ww[k], b2f(rr[k].y), ay);
            }
        }
        for (; t < cnt; ++t) {
            int j = __shfl(jv, t);
            float w = __shfl(wv, t);
            ushort2 r = T2[(size_t)j * 64 + f];
            ax = fmaf(w, b2f(r.x), ax);
            ay = fmaf(w, b2f(r.y), ay);
        }
    }

    float di = dinv[i];
    ushort2 selfr = T2[(size_t)i * 64 + f];
    float2 bv = ((const float2*)bias)[f];
    float rx = di * ax + di * di * b2f(selfr.x) + bv.x;
    float ry = di * ay + di * di * b2f(selfr.y) + bv.y;
    if (mode) {
        rx = fmaxf(rx, 0.f);
        ry = fmaxf(ry, 0.f);
        ushort2 h, l;
        h.x = f2b(rx); l.x = f2b(rx - b2f(h.x));
        h.y = f2b(ry); l.y = f2b(ry - b2f(h.y));
        ((ushort2*)Oh)[(size_t)i * 64 + f] = h;
        ((ushort2*)Ol)[(size_t)i * 64 + f] = l;
    } else {
        float2 res;
        res.x = rx;
        res.y = ry;
        ((float2*)Of)[(size_t)i * 64 + f] = res;
    }
}

// ---------------- launch ----------------

static inline char* carve(char*& w, size_t bytes) {
    char* p = w;
    w += (bytes + 255) & ~(size_t)255;
    return p;
}

extern "C" void kernel_launch(void* const* d_in, const int* in_sizes, int n_in,
                              void* d_out, int out_size, void* d_ws, size_t ws_size,
                              hipStream_t stream) {
    const float* x  = (const float*)d_in[0];
    const int*   ei = (const int*)d_in[1];
    const float* q  = (const float*)d_in[2];
    const float* W1 = (const float*)d_in[3];
    const float* b1 = (const float*)d_in[4];
    const float* W2 = (const float*)d_in[5];
    const float* b2 = (const float*)d_in[6];
    const float* Wq = (const float*)d_in[7];
    const float* bq = (const float*)d_in[8];

    int N  = in_sizes[0] / D;  // 50000
    int E  = in_sizes[1] / 2;  // 800000
    int MQ = in_sizes[2] / D;  // 20000

    const int* srcv = ei;
    const int* dstv = ei + E;

    char* w = (char*)d_ws;
    unsigned short* Cb   = (unsigned short*)carve(w, (size_t)N * D * 2);  // t1/t2 bf16
    unsigned short* Hb   = (unsigned short*)carve(w, (size_t)N * D * 2);  // h1-hi
    unsigned short* Lb   = (unsigned short*)carve(w, (size_t)N * D * 2);  // h1-lo
    int*            colv = (int*)carve(w, (size_t)E * 4);
    int*            cnt  = (int*)carve(w, (size_t)N * 4);
    int*            rs   = (int*)carve(w, (size_t)(N + 1) * 4);
    int*            fp   = (int*)carve(w, (size_t)N * 4);
    float*          dinv = (float*)carve(w, (size_t)N * 4);
    int*            bsum = (int*)carve(w, 256 * 4);
    int*            boff = (int*)carve(w, 256 * 4);
    unsigned short* Wth1 = (unsigned short*)carve(w, D * D * 2);
    unsigned short* Wth2 = (unsigned short*)carve(w, D * D * 2);
    unsigned short* Wthq = (unsigned short*)carve(w, D * D * 2);

    float* outq = (float*)d_out;
    float* outh = outq + (size_t)MQ * D;

    int nb  = (N + 1023) / 1024;   // 49
    int nps = (N + NS - 1) / NS;   // nodes per fill slice
    int nbN = (N + 63) / 64;       // 782
    int nbQ = (MQ + 63) / 64;      // 313

    // graph preprocessing
    hipMemsetAsync(cnt, 0, (size_t)N * 4, stream);
    hist_kernel<<<(E + 255) / 256, 256, 0, stream>>>(dstv, cnt, E);
    scan1_wsplit<<<nb + 192, 256, 0, stream>>>(cnt, bsum, N, nb, W1, W2, Wq, Wth1, Wth2, Wthq);
    scan_phase2<<<1, 256, 0, stream>>>(bsum, boff, rs, nb, N);
    scan_phase3<<<nb, 256, 0, stream>>>(cnt, boff, rs, fp, dinv, N);
    fill_sliced<<<128 * NS, 256, 0, stream>>>(srcv, dstv, fp, colv, E, nps);

    // conv1 GEMM + ques GEMM fused in one dispatch
    gemm1q<<<nbN + nbQ, 256, 0, stream>>>(x, q, Wth1, Wthq, bq, Cb, outq, N, MQ, nbN);
    aggregate<<<(N + 7) / 8, 512, 0, stream>>>(Cb, colv, rs, dinv, b1, nullptr, Hb, Lb, N, 1);

    // conv2: t2 = h1@W2 (bf16) ; h2 = agg(t2)+b2 -> fp32 out
    gemm2<<<nbN, 256, 0, stream>>>(Hb, Lb, Wth2, Cb, N);
    aggregate<<<(N + 7) / 8, 512, 0, stream>>>(Cb, colv, rs, dinv, b2, outh, nullptr, nullptr, N, 0);
}